// Round 10
// baseline (6237.105 us; speedup 1.0000x reference)
//
#include <hip/hip_runtime.h>
#include <stdint.h>

// Seq2seq LSTM, f32 in/out, bf16 MFMA, fp32 cell state.
// R19 = R18 + (a) replica selected by HW_REG_XCC_ID (not blockIdx&7 dispatch
// assumption) and (b) per-step phase-lock re-added (R15's null was confounded
// by spill; spill is now gone - WRITE_SIZE 900MB->176KB in R18).
//  R18 result: dec FETCH 5.39GB (56% L2 hit on a 1.5MB/XCD working set) ->
//  decoder is L2-miss-bound at 1.65TB/s. Suspects: replica<->XCD mismatch
//  (if dispatch isn't round-robin, an XCD sees up to 12MB > 4MB L2 = thrash)
//  and inter-block drift. Both addressed here.
//  Decoder: 128 blocks x 32 rows, full hid; h0/h1 LDS double-buffer;
//  c0/c1 in regs; weights streamed from per-XCD pk replica.
//  Encoder: unchanged (persistent, single-wave poll barrier). ~2.39 ms.

typedef short short8v __attribute__((ext_vector_type(8)));
typedef float float4v __attribute__((ext_vector_type(4)));
typedef unsigned long long u64;
#define MFMA(a,b,c) __builtin_amdgcn_mfma_f32_16x16x32_bf16((a),(b),(c),0,0,0)

#define HIDN 256
#define TLEN 512
#define HPE  ((size_t)256 * HIDN)     // enc h slot elements (128 KB)
#define LDP  264                      // dec LDS row pitch (bf16 elems)
#define PKREP 786432                  // pk replica stride (elements) = 1.5 MB

// B-frag load from packed weights: element ((n*8+kc)*64+lane)*8
#define BF(matp, n, kc) \
    (*(const short8v*)&(matp)[((size_t)(((((n) << 3) + (kc)) << 6) + lane)) << 3])

__device__ __forceinline__ unsigned short f2b(float f) {
    unsigned int u = __float_as_uint(f);
    unsigned int r = ((u >> 16) & 1u) + 0x7FFFu;
    return (unsigned short)((u + r) >> 16);
}
__device__ __forceinline__ float sigf(float x) { return 1.0f / (1.0f + __expf(-x)); }
__device__ __forceinline__ float tanhf2(float x) { return 1.0f - 2.0f / (1.0f + __expf(2.0f * x)); }

__device__ __forceinline__ void hpair_store(unsigned short* buf, int row, int hid,
                                            float h, int lane) {
    unsigned int mine = f2b(h);
    unsigned int part = (unsigned int)__shfl_xor((int)mine, 1);
    if (!(lane & 1)) {
        __hip_atomic_store((unsigned int*)&buf[(size_t)row * HIDN + hid],
                           mine | (part << 16),
                           __ATOMIC_RELAXED, __HIP_MEMORY_SCOPE_AGENT);
    }
}

// single-wave poll barrier (encoder)
__device__ __forceinline__ void bar_sync(unsigned int* fl, int slot, unsigned int target,
                                         int nfl, int lane, int tid, int& dead) {
    __syncthreads();
    if (tid == 0)
        __hip_atomic_store(&fl[slot], target, __ATOMIC_RELAXED, __HIP_MEMORY_SCOPE_AGENT);
    if (tid < 64 && !dead) {
        int guard = 0;
        for (;;) {
            unsigned int v = 0xFFFFFFFFu;
            if (lane < nfl)
                v = __hip_atomic_load(&fl[lane], __ATOMIC_RELAXED, __HIP_MEMORY_SCOPE_AGENT);
            if (__ballot(v >= target) == ~0ull) break;
            if (++guard > (1 << 20)) { dead = 1; break; }
        }
    }
    __syncthreads();
    __builtin_amdgcn_fence(__ATOMIC_ACQUIRE, "workgroup");
}

// decoder phase-lock: perf-only rendezvous of 128 blocks (no inter-block data
// -> no fence needed). Wave 0 lane l polls flags[l] and flags[64+l].
__device__ __forceinline__ void dec_lock(unsigned int* fl, int bid, unsigned int target,
                                         int lane, int tid, int& dead) {
    __syncthreads();
    if (tid == 0)
        __hip_atomic_store(&fl[bid], target, __ATOMIC_RELAXED, __HIP_MEMORY_SCOPE_AGENT);
    if (tid < 64 && !dead) {
        int guard = 0;
        for (;;) {
            unsigned int a = __hip_atomic_load(&fl[lane], __ATOMIC_RELAXED,
                                               __HIP_MEMORY_SCOPE_AGENT);
            unsigned int b = __hip_atomic_load(&fl[64 + lane], __ATOMIC_RELAXED,
                                               __HIP_MEMORY_SCOPE_AGENT);
            unsigned int v = a < b ? a : b;
            if (__ballot(v >= target) == ~0ull) break;
            if (++guard > (1 << 18)) { dead = 1; break; }
        }
    }
    __syncthreads();
}

// ==================== DEC WEIGHT PACK (one-time, 8 replicas) ====================
// pk slot = ((mat*64 + n)*8 + kc)*64 + lane; element W[n*16+(lane&15)][kc*32+(lane>>4)*8+i]
__global__ __launch_bounds__(256) void pack_kernel(
    const float* __restrict__ Whh0, const float* __restrict__ Wih1,
    const float* __restrict__ Whh1, unsigned short* __restrict__ pk)
{
    int gid = blockIdx.x * 256 + threadIdx.x;   // 0..98303
    int lane = gid & 63;
    int kc = (gid >> 6) & 7;
    int n  = (gid >> 9) & 63;
    int mat = gid >> 15;
    const float* W = (mat == 0) ? Whh0 : ((mat == 1) ? Wih1 : Whh1);
    const float* p = W + (size_t)(n * 16 + (lane & 15)) * HIDN
                       + (kc << 5) + ((lane >> 4) << 3);
    short8v v;
#pragma unroll
    for (int i = 0; i < 8; ++i) v[i] = (short)f2b(p[i]);
#pragma unroll
    for (int rep = 0; rep < 8; ++rep)
        *(short8v*)&pk[(size_t)rep * PKREP + ((size_t)gid << 3)] = v;
}

// ============================ ENCODER (unchanged) ============================
__global__ __launch_bounds__(256, 1) void enc_kernel(
    const float* __restrict__ x,
    const float* __restrict__ Wih0, const float* __restrict__ Whh0, const float* __restrict__ b0,
    const float* __restrict__ Wih1, const float* __restrict__ Whh1, const float* __restrict__ b1,
    unsigned short* __restrict__ h0e, unsigned short* __restrict__ h1e,
    unsigned short* __restrict__ finh0, unsigned short* __restrict__ finh1,
    float* __restrict__ finc0, float* __restrict__ finc1,
    unsigned int* __restrict__ flags)
{
    const int tid = threadIdx.x, lane = tid & 63, wv = tid >> 6;
    const int bt = blockIdx.x & 15, hs = blockIdx.x >> 4;
    const int row0 = bt << 4, hidb = hs << 4;
    const int l15 = lane & 15, q = lane >> 4, q8 = q << 3;

    __shared__ float gt[12][16][17];
    __shared__ float xt[16][TLEN + 1];
    __shared__ unsigned short hst0[16][264], hst1[16][264];

    for (int idx = tid; idx < 16 * TLEN; idx += 256) {
        int r = idx >> 9, c = idx & 511;
        xt[r][c] = x[(size_t)(row0 + r) * TLEN + c];
    }

    short8v wf[3][8];
    {
        const float* Ws[3] = {Whh0, Wih1, Whh1};
#pragma unroll
        for (int j = 0; j < 3; ++j) {
            int p = wv * 3 + j;
            int mat = p >> 2, g = p & 3;
            const float* rp = Ws[mat] + (size_t)((g << 8) + hidb + l15) * HIDN + q8;
#pragma unroll
            for (int kc = 0; kc < 8; ++kc) {
                short8v v;
#pragma unroll
                for (int i = 0; i < 8; ++i) v[i] = (short)f2b(rp[(kc << 5) + i]);
                wf[j][kc] = v;
            }
        }
    }

    const int erow = tid >> 4, ehid = tid & 15;
    const int grow = row0 + erow, ghid = hidb + ehid;
    float wx[4], bb0v[4], bb1v[4];
#pragma unroll
    for (int g = 0; g < 4; ++g) {
        wx[g]   = Wih0[(g << 8) + ghid];
        bb0v[g] = b0[(g << 8) + ghid];
        bb1v[g] = b1[(g << 8) + ghid];
    }
    float c0 = 0.f, c1 = 0.f;
    unsigned int* fl = flags + (bt << 4);
    int dead = 0;
    const bool useH0 = (wv <= 2), useH1 = (wv >= 2);
    __syncthreads();

    for (int s = 1; s <= 513; ++s) {
        const unsigned short* hr0 = h0e + (size_t)((s - 1) & 1) * HPE;
        const unsigned short* hr1 = h1e + (size_t)((s - 1) & 1) * HPE;
        unsigned short* hw0 = h0e + (size_t)(s & 1) * HPE;
        unsigned short* hw1 = h1e + (size_t)(s & 1) * HPE;

        if (s >= 2) {
#pragma unroll
            for (int k = 0; k < 4; ++k) {
                int oo = tid + (k << 8);
                int r = oo >> 6, cu = oo & 63;
                u64 v = __hip_atomic_load((const u64*)&hr0[(size_t)(row0 + r) * HIDN + (cu << 2)],
                                          __ATOMIC_RELAXED, __HIP_MEMORY_SCOPE_AGENT);
                *(u64*)&hst0[r][cu << 2] = v;
            }
        }
        if (s >= 3) {
#pragma unroll
            for (int k = 0; k < 4; ++k) {
                int oo = tid + (k << 8);
                int r = oo >> 6, cu = oo & 63;
                u64 v = __hip_atomic_load((const u64*)&hr1[(size_t)(row0 + r) * HIDN + (cu << 2)],
                                          __ATOMIC_RELAXED, __HIP_MEMORY_SCOPE_AGENT);
                *(u64*)&hst1[r][cu << 2] = v;
            }
        }
        __syncthreads();

        float4v acc[3] = {{0,0,0,0},{0,0,0,0},{0,0,0,0}};
        short8v a0f[8], a1f[8];
        if (useH0 && s >= 2) {
#pragma unroll
            for (int kc = 0; kc < 8; ++kc) a0f[kc] = *(const short8v*)&hst0[l15][(kc << 5) + q8];
        }
        if (useH1 && s >= 3) {
#pragma unroll
            for (int kc = 0; kc < 8; ++kc) a1f[kc] = *(const short8v*)&hst1[l15][(kc << 5) + q8];
        }
#pragma unroll
        for (int j = 0; j < 3; ++j) {
            int p = wv * 3 + j;
            int mat = p >> 2;
            bool active = (mat == 0) ? (s >= 2 && s <= 512)
                        : (mat == 1) ? (s >= 2)
                                     : (s >= 3);
            if (active) {
                if (mat == 2) {
#pragma unroll
                    for (int kc = 0; kc < 8; ++kc) acc[j] = MFMA(a1f[kc], wf[j][kc], acc[j]);
                } else {
#pragma unroll
                    for (int kc = 0; kc < 8; ++kc) acc[j] = MFMA(a0f[kc], wf[j][kc], acc[j]);
                }
            }
        }
#pragma unroll
        for (int j = 0; j < 3; ++j) {
            int p = wv * 3 + j;
#pragma unroll
            for (int r = 0; r < 4; ++r) gt[p][(q << 2) + r][l15] = acc[j][r];
        }
        __syncthreads();

        if (s <= 512) {
            float xv = xt[erow][s - 1];
            float gi = gt[0][erow][ehid] + wx[0] * xv + bb0v[0];
            float gf = gt[1][erow][ehid] + wx[1] * xv + bb0v[1];
            float gg = gt[2][erow][ehid] + wx[2] * xv + bb0v[2];
            float go = gt[3][erow][ehid] + wx[3] * xv + bb0v[3];
            c0 = sigf(gf) * c0 + sigf(gi) * tanhf2(gg);
            float h0n = sigf(go) * tanhf2(c0);
            hpair_store(hw0, grow, ghid, h0n, lane);
            if (s == 512) {
                finh0[(size_t)grow * HIDN + ghid] = f2b(h0n);
                finc0[(size_t)grow * HIDN + ghid] = c0;
            }
        }
        if (s >= 2) {
            float gi = gt[4][erow][ehid] + gt[8][erow][ehid]  + bb1v[0];
            float gf = gt[5][erow][ehid] + gt[9][erow][ehid]  + bb1v[1];
            float gg = gt[6][erow][ehid] + gt[10][erow][ehid] + bb1v[2];
            float go = gt[7][erow][ehid] + gt[11][erow][ehid] + bb1v[3];
            c1 = sigf(gf) * c1 + sigf(gi) * tanhf2(gg);
            float h1n = sigf(go) * tanhf2(c1);
            hpair_store(hw1, grow, ghid, h1n, lane);
            if (s == 513) {
                finh1[(size_t)grow * HIDN + ghid] = f2b(h1n);
                finc1[(size_t)grow * HIDN + ghid] = c1;
            }
        }
        bar_sync(fl, hs, (unsigned int)s, 16, lane, tid, dead);
    }
}

// ===================== ROW-LOCAL DECODER (32 rows/block) =====================
// 128 blocks x 512 threads. Block owns rows [blk*32, blk*32+32), full hid.
// Wave w owns hid [w*32,(w+1)*32) = 2 chunks (hf = 2w+ch); m in {0,1} covers
// 32 rows. h0/h1 double-buffered in LDS. Weights streamed from the replica of
// THIS block's physical XCD (HW_REG_XCC_ID). Per-step phase-lock (perf-only).
__global__ __launch_bounds__(512, 1) void dec_kernel(
    const unsigned short* __restrict__ pk,
    const float* __restrict__ Wih0, const float* __restrict__ b0,
    const float* __restrict__ b1, const float* __restrict__ outW,
    const float* __restrict__ outb, const float* __restrict__ dinit,
    const unsigned short* __restrict__ finh0, const float* __restrict__ finc0,
    const unsigned short* __restrict__ finh1, const float* __restrict__ finc1,
    unsigned int* __restrict__ flags, float* __restrict__ out)
{
    extern __shared__ char smem[];
    unsigned short* h0A = (unsigned short*)smem;            // [32][LDP]
    unsigned short* h0B = h0A + 32 * LDP;
    unsigned short* h1A = h0B + 32 * LDP;
    unsigned short* h1B = h1A + 32 * LDP;
    float* predp = (float*)(smem + 4 * 32 * LDP * 2);       // [8][32]
    float* inpl  = predp + 8 * 32;                          // [32]

    const int tid = threadIdx.x, lane = tid & 63, wv = tid >> 6;
    const int l15 = lane & 15, q = lane >> 4, q8 = q << 3;
    const int row0 = blockIdx.x << 5;
    const float outb_v = outb[0];

    // replica = physical XCD id (hardware truth, not dispatch assumption)
    unsigned int xcc;
    asm volatile("s_getreg_b32 %0, hwreg(HW_REG_XCC_ID)" : "=s"(xcc));
    const unsigned short* pkr = pk + (size_t)(xcc & 7) * PKREP;
    const unsigned short* pkm0 = pkr;
    const unsigned short* pkm1 = pkr + 262144;
    const unsigned short* pkm2 = pkr + 524288;

    // init: h0A/h1A from enc finals (32 rows x 64 u64 chunks = full 256 hid)
    for (int idx = tid; idx < 32 * 64; idx += 512) {
        int r = idx >> 6, cu = idx & 63;
        u64 v0 = *(const u64*)&finh0[(size_t)((row0 + r) & 255) * HIDN + (cu << 2)];
        u64 v1 = *(const u64*)&finh1[(size_t)((row0 + r) & 255) * HIDN + (cu << 2)];
        *(u64*)&h0A[r * LDP + (cu << 2)] = v0;
        *(u64*)&h1A[r * LDP + (cu << 2)] = v1;
    }
    if (tid < 32) inpl[tid] = dinit[row0 + tid];

    // per-thread constants and cell state: hid = (2wv+ch)*16+l15, rows
    // (m<<4)+(q<<2)+r  (m in {0,1})
    float wx[2][4], bb0v[2][4], bb1v[2][4], ow[2];
    float c0r[2][2][4], c1r[2][2][4];   // [ch][m][r] = 16+16 floats
#pragma unroll
    for (int ch = 0; ch < 2; ++ch) {
        int hid = (((wv << 1) + ch) << 4) + l15;
        ow[ch] = outW[hid];
#pragma unroll
        for (int g = 0; g < 4; ++g) {
            wx[ch][g]   = Wih0[(g << 8) + hid];
            bb0v[ch][g] = b0[(g << 8) + hid];
            bb1v[ch][g] = b1[(g << 8) + hid];
        }
#pragma unroll
        for (int m = 0; m < 2; ++m)
#pragma unroll
            for (int r = 0; r < 4; ++r) {
                int b = (row0 + (m << 4) + (q << 2) + r) & 255;
                c0r[ch][m][r] = finc0[(size_t)b * HIDN + hid];
                c1r[ch][m][r] = finc1[(size_t)b * HIDN + hid];
            }
    }
    int dead = 0;
    __syncthreads();

    for (int t = 0; t < 64; ++t) {
        const unsigned short* h0r = (t & 1) ? h0B : h0A;
        unsigned short*       h0w = (t & 1) ? h0A : h0B;
        const unsigned short* h1r = (t & 1) ? h1B : h1A;
        unsigned short*       h1w = (t & 1) ? h1A : h1B;

        float inpr[2][4];
#pragma unroll
        for (int m = 0; m < 2; ++m)
#pragma unroll
            for (int r = 0; r < 4; ++r)
                inpr[m][r] = inpl[(m << 4) + (q << 2) + r];

        // ---- layer 0: acc = h0(t-1)@Whh0 ; cell0 -> h0(t) direct to h0w ----
#pragma unroll
        for (int ch = 0; ch < 2; ++ch) {
            const int hf = (wv << 1) + ch;
            float4v acc[2][4];
#pragma unroll
            for (int m = 0; m < 2; ++m)
#pragma unroll
                for (int g = 0; g < 4; ++g) acc[m][g] = (float4v){0, 0, 0, 0};
#pragma unroll
            for (int kc = 0; kc < 8; ++kc) {
                short8v a0 = *(const short8v*)&h0r[(l15) * LDP + (kc << 5) + q8];
                short8v a1 = *(const short8v*)&h0r[(16 + l15) * LDP + (kc << 5) + q8];
#pragma unroll
                for (int g = 0; g < 4; ++g) {
                    short8v bf = BF(pkm0, (g << 4) + hf, kc);
                    acc[0][g] = MFMA(a0, bf, acc[0][g]);
                    acc[1][g] = MFMA(a1, bf, acc[1][g]);
                }
            }
            const int hid = (hf << 4) + l15;
#pragma unroll
            for (int m = 0; m < 2; ++m)
#pragma unroll
                for (int r = 0; r < 4; ++r) {
                    float inp = inpr[m][r];
                    float gi = acc[m][0][r] + wx[ch][0] * inp + bb0v[ch][0];
                    float gf = acc[m][1][r] + wx[ch][1] * inp + bb0v[ch][1];
                    float gg = acc[m][2][r] + wx[ch][2] * inp + bb0v[ch][2];
                    float go = acc[m][3][r] + wx[ch][3] * inp + bb0v[ch][3];
                    float cn = sigf(gf) * c0r[ch][m][r] + sigf(gi) * tanhf2(gg);
                    c0r[ch][m][r] = cn;
                    float h0n = sigf(go) * tanhf2(cn);
                    unsigned int mine = f2b(h0n);
                    unsigned int part = (unsigned int)__shfl_xor((int)mine, 1);
                    if (!(l15 & 1))
                        *(unsigned int*)&h0w[((m << 4) + (q << 2) + r) * LDP + hid] =
                            mine | (part << 16);
                }
        }
        __syncthreads();   // h0(t) visible; h0r reads done

        // ---- layer 1: acc = h0(t)@Wih1 + h1(t-1)@Whh1 ; cell1 + pred ----
        float pp[2][4] = {{0,0,0,0},{0,0,0,0}};
#pragma unroll
        for (int ch = 0; ch < 2; ++ch) {
            const int hf = (wv << 1) + ch;
            float4v acc[2][4];
#pragma unroll
            for (int m = 0; m < 2; ++m)
#pragma unroll
                for (int g = 0; g < 4; ++g) acc[m][g] = (float4v){0, 0, 0, 0};
#pragma unroll
            for (int kc = 0; kc < 8; ++kc) {
                short8v a0 = *(const short8v*)&h0w[(l15) * LDP + (kc << 5) + q8];
                short8v a1 = *(const short8v*)&h0w[(16 + l15) * LDP + (kc << 5) + q8];
#pragma unroll
                for (int g = 0; g < 4; ++g) {
                    short8v bf = BF(pkm1, (g << 4) + hf, kc);
                    acc[0][g] = MFMA(a0, bf, acc[0][g]);
                    acc[1][g] = MFMA(a1, bf, acc[1][g]);
                }
            }
#pragma unroll
            for (int kc = 0; kc < 8; ++kc) {
                short8v a0 = *(const short8v*)&h1r[(l15) * LDP + (kc << 5) + q8];
                short8v a1 = *(const short8v*)&h1r[(16 + l15) * LDP + (kc << 5) + q8];
#pragma unroll
                for (int g = 0; g < 4; ++g) {
                    short8v bf = BF(pkm2, (g << 4) + hf, kc);
                    acc[0][g] = MFMA(a0, bf, acc[0][g]);
                    acc[1][g] = MFMA(a1, bf, acc[1][g]);
                }
            }
            const int hid = (hf << 4) + l15;
#pragma unroll
            for (int m = 0; m < 2; ++m)
#pragma unroll
                for (int r = 0; r < 4; ++r) {
                    float gi = acc[m][0][r] + bb1v[ch][0];
                    float gf = acc[m][1][r] + bb1v[ch][1];
                    float gg = acc[m][2][r] + bb1v[ch][2];
                    float go = acc[m][3][r] + bb1v[ch][3];
                    float cn = sigf(gf) * c1r[ch][m][r] + sigf(gi) * tanhf2(gg);
                    c1r[ch][m][r] = cn;
                    float h1n = sigf(go) * tanhf2(cn);
                    pp[m][r] += h1n * ow[ch];
                    unsigned int mine = f2b(h1n);
                    unsigned int part = (unsigned int)__shfl_xor((int)mine, 1);
                    if (!(l15 & 1))
                        *(unsigned int*)&h1w[((m << 4) + (q << 2) + r) * LDP + hid] =
                            mine | (part << 16);
                }
        }
        // pred: reduce over l15 (32 hid per wave already in-thread via ch)
#pragma unroll
        for (int off = 1; off < 16; off <<= 1)
#pragma unroll
            for (int m = 0; m < 2; ++m)
#pragma unroll
                for (int r = 0; r < 4; ++r) pp[m][r] += __shfl_xor(pp[m][r], off);
        if (l15 == 0) {
#pragma unroll
            for (int m = 0; m < 2; ++m)
#pragma unroll
                for (int r = 0; r < 4; ++r)
                    predp[(wv << 5) + (m << 4) + (q << 2) + r] = pp[m][r];
        }
        __syncthreads();   // h1(t) + wave partials visible; h1r reads done
        if (tid < 32) {
            float s = predp[tid];
#pragma unroll
            for (int w = 1; w < 8; ++w) s += predp[(w << 5) + tid];
            s += outb_v;
            inpl[tid] = s;
            int row = row0 + tid;
            out[(size_t)(((row & 255) << 4) + (row >> 8)) * 64 + t] = s;
        }
        // phase-lock (perf-only): bound inter-block drift so same-XCD blocks
        // share the L2-resident replica. Publishes inp(t+1) via internal syncs.
        dec_lock(flags, blockIdx.x, (unsigned int)(t + 1), lane, tid, dead);
    }
}

extern "C" void kernel_launch(void* const* d_in, const int* in_sizes, int n_in,
                              void* d_out, int out_size, void* d_ws, size_t ws_size,
                              hipStream_t stream) {
    (void)in_sizes; (void)n_in; (void)out_size; (void)ws_size;
    const float* x     = (const float*)d_in[0];
    const float* eWih0 = (const float*)d_in[1];
    const float* eWhh0 = (const float*)d_in[2];
    const float* eb0   = (const float*)d_in[3];
    const float* eWih1 = (const float*)d_in[4];
    const float* eWhh1 = (const float*)d_in[5];
    const float* eb1   = (const float*)d_in[6];
    const float* dWih0 = (const float*)d_in[7];
    const float* dWhh0 = (const float*)d_in[8];
    const float* db0   = (const float*)d_in[9];
    const float* dWih1 = (const float*)d_in[10];
    const float* dWhh1 = (const float*)d_in[11];
    const float* db1   = (const float*)d_in[12];
    const float* outW  = (const float*)d_in[13];
    const float* outb  = (const float*)d_in[14];
    const float* dinit = (const float*)d_in[15];

    char* ws = (char*)d_ws;
    unsigned short* h0e   = (unsigned short*)(ws);               // 256 KB
    unsigned short* h1e   = (unsigned short*)(ws + 262144);      // 256 KB
    unsigned short* finh0 = (unsigned short*)(ws + 524288);      // 128 KB
    unsigned short* finh1 = (unsigned short*)(ws + 655360);      // 128 KB
    float* finc0          = (float*)(ws + 786432);               // 256 KB
    float* finc1          = (float*)(ws + 1048576);              // 256 KB
    unsigned int* fle     = (unsigned int*)(ws + 1310720);       // 1 KB
    unsigned short* pk    = (unsigned short*)(ws + 1311744);     // 12 MB (8 replicas)
    unsigned int* fld     = (unsigned int*)(ws + 13894656);      // 512 B (128 flags)

    hipMemsetAsync(fle, 0, 1024, stream);
    hipMemsetAsync(fld, 0, 512, stream);

    const int dec_lds = 4 * 32 * LDP * 2 + 8 * 32 * 4 + 32 * 4;  // 68736 B
    hipFuncSetAttribute((const void*)dec_kernel,
                        hipFuncAttributeMaxDynamicSharedMemorySize, dec_lds);

    pack_kernel<<<384, 256, 0, stream>>>(dWhh0, dWih1, dWhh1, pk);
    enc_kernel<<<256, 256, 0, stream>>>(x, eWih0, eWhh0, eb0, eWih1, eWhh1, eb1,
                                        h0e, h1e, finh0, finh1, finc0, finc1, fle);
    dec_kernel<<<128, 512, dec_lds, stream>>>(pk, dWih0, db0, db1, outW, outb, dinit,
                                              finh0, finc0, finh1, finc1,
                                              fld, (float*)d_out);
}

// Round 12
// 4679.835 us; speedup vs baseline: 1.3328x; 1.3328x over previous
//
#include <hip/hip_runtime.h>
#include <stdint.h>

// Seq2seq LSTM, f32 in/out, bf16 MFMA, fp32 cell state.
// R21 = R20 resubmission (container infra failure x2; kernel audit clean).
//  Only change: decoder barrier guard 2^20 -> 2^16 so a broken run bails in
//  ~ms instead of masquerading as a hang under the timing loop.
//  Decoder: R12 hid-sliced structure + XCD-LOCAL h exchange via L2.
//   Each row-group's 8 hid-slice blocks pinned to ONE XCD via work queue
//   (HW_REG_XCC_ID + per-XCD slot counter; exact 32 blocks/XCD from
//   1-block/CU occupancy at 128KB LDS). h/pred exchange through that XCD's
//   L2: plain stores (drained by barrier vmcnt) + inline-asm sc0 loads
//   (bypass L1, hit L2). Flags stay on the proven LLC agent-atomic path.
//  Encoder: unchanged (persistent, single-wave poll barrier). ~2.39 ms.

typedef short short8v __attribute__((ext_vector_type(8)));
typedef float float4v __attribute__((ext_vector_type(4)));
typedef unsigned long long u64;
#define MFMA(a,b,c) __builtin_amdgcn_mfma_f32_16x16x32_bf16((a),(b),(c),0,0,0)

#define HIDN 256
#define TLEN 512
#define HPE  ((size_t)256 * HIDN)     // enc h slot elements (128 KB)
#define HPD  ((size_t)4096 * HIDN)    // dec h slot elements (2 MB bf16)
#define PKREP 786432                  // pk replica stride (elements) = 1.5 MB

__device__ __forceinline__ unsigned short f2b(float f) {
    unsigned int u = __float_as_uint(f);
    unsigned int r = ((u >> 16) & 1u) + 0x7FFFu;
    return (unsigned short)((u + r) >> 16);
}
__device__ __forceinline__ float sigf(float x) { return 1.0f / (1.0f + __expf(-x)); }
__device__ __forceinline__ float tanhf2(float x) { return 1.0f - 2.0f / (1.0f + __expf(2.0f * x)); }

// ---- XCD-local (sc0: L1-bypass, L2-hit) loaders; batch-drained ----
__device__ __forceinline__ short8v ld16_sc0(const unsigned short* p) {
    short8v v;
    asm volatile("global_load_dwordx4 %0, %1, off sc0" : "=&v"(v) : "v"(p) : "memory");
    return v;
}
__device__ __forceinline__ float4v ld16f_sc0(const float* p) {
    float4v v;
    asm volatile("global_load_dwordx4 %0, %1, off sc0" : "=&v"(v) : "v"(p) : "memory");
    return v;
}
__device__ __forceinline__ void vm_drain() {
    asm volatile("s_waitcnt vmcnt(0)" ::: "memory");
    __builtin_amdgcn_sched_barrier(0);
}

// agent-atomic h store (encoder path, unchanged)
__device__ __forceinline__ void hpair_store(unsigned short* buf, int row, int hid,
                                            float h, int lane) {
    unsigned int mine = f2b(h);
    unsigned int part = (unsigned int)__shfl_xor((int)mine, 1);
    if (!(lane & 1)) {
        __hip_atomic_store((unsigned int*)&buf[(size_t)row * HIDN + hid],
                           mine | (part << 16),
                           __ATOMIC_RELAXED, __HIP_MEMORY_SCOPE_AGENT);
    }
}
// plain h store (decoder: write-through L1 -> producer XCD L2)
__device__ __forceinline__ void hpair_plain(unsigned short* buf, int row, int hid,
                                            float h, int lane) {
    unsigned int mine = f2b(h);
    unsigned int part = (unsigned int)__shfl_xor((int)mine, 1);
    if (!(lane & 1))
        *(unsigned int*)&buf[(size_t)row * HIDN + hid] = mine | (part << 16);
}

// single-wave poll barrier (flags via LLC agent atomics, proven)
__device__ __forceinline__ void bar_sync(unsigned int* fl, int slot, unsigned int target,
                                         int nfl, int lane, int tid, int& dead,
                                         int guard_lim) {
    __syncthreads();   // drains vmcnt: all prior stores are in L2 (or LLC)
    if (tid == 0)
        __hip_atomic_store(&fl[slot], target, __ATOMIC_RELAXED, __HIP_MEMORY_SCOPE_AGENT);
    if (tid < 64 && !dead) {
        int guard = 0;
        for (;;) {
            unsigned int v = 0xFFFFFFFFu;
            if (lane < nfl)
                v = __hip_atomic_load(&fl[lane], __ATOMIC_RELAXED, __HIP_MEMORY_SCOPE_AGENT);
            if (__ballot(v >= target) == ~0ull) break;
            if (++guard > guard_lim) { dead = 1; break; }
        }
    }
    __syncthreads();
    __builtin_amdgcn_fence(__ATOMIC_ACQUIRE, "workgroup");
}

// ==================== DEC WEIGHT PACK (one-time, 8 replicas) ====================
// pk slot = ((mat*64 + n)*8 + kc)*64 + lane; element W[n*16+(lane&15)][kc*32+(lane>>4)*8+i]
__global__ __launch_bounds__(256) void pack_kernel(
    const float* __restrict__ Whh0, const float* __restrict__ Wih1,
    const float* __restrict__ Whh1, unsigned short* __restrict__ pk)
{
    int gid = blockIdx.x * 256 + threadIdx.x;   // 0..98303
    int lane = gid & 63;
    int kc = (gid >> 6) & 7;
    int n  = (gid >> 9) & 63;
    int mat = gid >> 15;
    const float* W = (mat == 0) ? Whh0 : ((mat == 1) ? Wih1 : Whh1);
    const float* p = W + (size_t)(n * 16 + (lane & 15)) * HIDN
                       + (kc << 5) + ((lane >> 4) << 3);
    short8v v;
#pragma unroll
    for (int i = 0; i < 8; ++i) v[i] = (short)f2b(p[i]);
#pragma unroll
    for (int rep = 0; rep < 8; ++rep)
        *(short8v*)&pk[(size_t)rep * PKREP + ((size_t)gid << 3)] = v;
}

// ============================ ENCODER (unchanged) ============================
__global__ __launch_bounds__(256, 1) void enc_kernel(
    const float* __restrict__ x,
    const float* __restrict__ Wih0, const float* __restrict__ Whh0, const float* __restrict__ b0,
    const float* __restrict__ Wih1, const float* __restrict__ Whh1, const float* __restrict__ b1,
    unsigned short* __restrict__ h0e, unsigned short* __restrict__ h1e,
    unsigned short* __restrict__ finh0, unsigned short* __restrict__ finh1,
    float* __restrict__ finc0, float* __restrict__ finc1,
    unsigned int* __restrict__ flags)
{
    const int tid = threadIdx.x, lane = tid & 63, wv = tid >> 6;
    const int bt = blockIdx.x & 15, hs = blockIdx.x >> 4;
    const int row0 = bt << 4, hidb = hs << 4;
    const int l15 = lane & 15, q = lane >> 4, q8 = q << 3;

    __shared__ float gt[12][16][17];
    __shared__ float xt[16][TLEN + 1];
    __shared__ unsigned short hst0[16][264], hst1[16][264];

    for (int idx = tid; idx < 16 * TLEN; idx += 256) {
        int r = idx >> 9, c = idx & 511;
        xt[r][c] = x[(size_t)(row0 + r) * TLEN + c];
    }

    short8v wf[3][8];
    {
        const float* Ws[3] = {Whh0, Wih1, Whh1};
#pragma unroll
        for (int j = 0; j < 3; ++j) {
            int p = wv * 3 + j;
            int mat = p >> 2, g = p & 3;
            const float* rp = Ws[mat] + (size_t)((g << 8) + hidb + l15) * HIDN + q8;
#pragma unroll
            for (int kc = 0; kc < 8; ++kc) {
                short8v v;
#pragma unroll
                for (int i = 0; i < 8; ++i) v[i] = (short)f2b(rp[(kc << 5) + i]);
                wf[j][kc] = v;
            }
        }
    }

    const int erow = tid >> 4, ehid = tid & 15;
    const int grow = row0 + erow, ghid = hidb + ehid;
    float wx[4], bb0v[4], bb1v[4];
#pragma unroll
    for (int g = 0; g < 4; ++g) {
        wx[g]   = Wih0[(g << 8) + ghid];
        bb0v[g] = b0[(g << 8) + ghid];
        bb1v[g] = b1[(g << 8) + ghid];
    }
    float c0 = 0.f, c1 = 0.f;
    unsigned int* fl = flags + (bt << 4);
    int dead = 0;
    const bool useH0 = (wv <= 2), useH1 = (wv >= 2);
    __syncthreads();

    for (int s = 1; s <= 513; ++s) {
        const unsigned short* hr0 = h0e + (size_t)((s - 1) & 1) * HPE;
        const unsigned short* hr1 = h1e + (size_t)((s - 1) & 1) * HPE;
        unsigned short* hw0 = h0e + (size_t)(s & 1) * HPE;
        unsigned short* hw1 = h1e + (size_t)(s & 1) * HPE;

        if (s >= 2) {
#pragma unroll
            for (int k = 0; k < 4; ++k) {
                int oo = tid + (k << 8);
                int r = oo >> 6, cu = oo & 63;
                u64 v = __hip_atomic_load((const u64*)&hr0[(size_t)(row0 + r) * HIDN + (cu << 2)],
                                          __ATOMIC_RELAXED, __HIP_MEMORY_SCOPE_AGENT);
                *(u64*)&hst0[r][cu << 2] = v;
            }
        }
        if (s >= 3) {
#pragma unroll
            for (int k = 0; k < 4; ++k) {
                int oo = tid + (k << 8);
                int r = oo >> 6, cu = oo & 63;
                u64 v = __hip_atomic_load((const u64*)&hr1[(size_t)(row0 + r) * HIDN + (cu << 2)],
                                          __ATOMIC_RELAXED, __HIP_MEMORY_SCOPE_AGENT);
                *(u64*)&hst1[r][cu << 2] = v;
            }
        }
        __syncthreads();

        float4v acc[3] = {{0,0,0,0},{0,0,0,0},{0,0,0,0}};
        short8v a0f[8], a1f[8];
        if (useH0 && s >= 2) {
#pragma unroll
            for (int kc = 0; kc < 8; ++kc) a0f[kc] = *(const short8v*)&hst0[l15][(kc << 5) + q8];
        }
        if (useH1 && s >= 3) {
#pragma unroll
            for (int kc = 0; kc < 8; ++kc) a1f[kc] = *(const short8v*)&hst1[l15][(kc << 5) + q8];
        }
#pragma unroll
        for (int j = 0; j < 3; ++j) {
            int p = wv * 3 + j;
            int mat = p >> 2;
            bool active = (mat == 0) ? (s >= 2 && s <= 512)
                        : (mat == 1) ? (s >= 2)
                                     : (s >= 3);
            if (active) {
                if (mat == 2) {
#pragma unroll
                    for (int kc = 0; kc < 8; ++kc) acc[j] = MFMA(a1f[kc], wf[j][kc], acc[j]);
                } else {
#pragma unroll
                    for (int kc = 0; kc < 8; ++kc) acc[j] = MFMA(a0f[kc], wf[j][kc], acc[j]);
                }
            }
        }
#pragma unroll
        for (int j = 0; j < 3; ++j) {
            int p = wv * 3 + j;
#pragma unroll
            for (int r = 0; r < 4; ++r) gt[p][(q << 2) + r][l15] = acc[j][r];
        }
        __syncthreads();

        if (s <= 512) {
            float xv = xt[erow][s - 1];
            float gi = gt[0][erow][ehid] + wx[0] * xv + bb0v[0];
            float gf = gt[1][erow][ehid] + wx[1] * xv + bb0v[1];
            float gg = gt[2][erow][ehid] + wx[2] * xv + bb0v[2];
            float go = gt[3][erow][ehid] + wx[3] * xv + bb0v[3];
            c0 = sigf(gf) * c0 + sigf(gi) * tanhf2(gg);
            float h0n = sigf(go) * tanhf2(c0);
            hpair_store(hw0, grow, ghid, h0n, lane);
            if (s == 512) {
                finh0[(size_t)grow * HIDN + ghid] = f2b(h0n);
                finc0[(size_t)grow * HIDN + ghid] = c0;
            }
        }
        if (s >= 2) {
            float gi = gt[4][erow][ehid] + gt[8][erow][ehid]  + bb1v[0];
            float gf = gt[5][erow][ehid] + gt[9][erow][ehid]  + bb1v[1];
            float gg = gt[6][erow][ehid] + gt[10][erow][ehid] + bb1v[2];
            float go = gt[7][erow][ehid] + gt[11][erow][ehid] + bb1v[3];
            c1 = sigf(gf) * c1 + sigf(gi) * tanhf2(gg);
            float h1n = sigf(go) * tanhf2(c1);
            hpair_store(hw1, grow, ghid, h1n, lane);
            if (s == 513) {
                finh1[(size_t)grow * HIDN + ghid] = f2b(h1n);
                finc1[(size_t)grow * HIDN + ghid] = c1;
            }
        }
        bar_sync(fl, hs, (unsigned int)s, 16, lane, tid, dead, 1 << 20);
    }
}

// ===================== PERSISTENT DECODER (XCD-local exchange) =====================
// 256 blocks x 256 threads, 1 block/CU. Work queue: xcd = HW_REG_XCC_ID,
// slot = atomicAdd(qcnt[xcd]) & 31 -> rg = xcd*4 + slot>>3 (128 rows),
// hsl = slot&7 (32 hid). All 8 hsl siblings of a rg share one XCD ->
// h/pred exchange via that XCD's L2 (plain stores + sc0 loads).
__global__ __launch_bounds__(256, 1) void dec_kernel(
    const unsigned short* __restrict__ pk,
    const float* __restrict__ Wih0, const float* __restrict__ b0,
    const float* __restrict__ b1, const float* __restrict__ outW,
    const float* __restrict__ outb, const float* __restrict__ dinit,
    const unsigned short* __restrict__ finh0, const float* __restrict__ finc0,
    const unsigned short* __restrict__ finh1, const float* __restrict__ finc1,
    unsigned short* __restrict__ h0d, unsigned short* __restrict__ h1d,
    float* __restrict__ predpart, unsigned int* __restrict__ flags,
    unsigned int* __restrict__ qcnt, float* __restrict__ out)
{
    extern __shared__ unsigned short wlds[];   // 128KB weights + 512B inpl
    float* inpl = (float*)&wlds[65536];        // [128] f32
    __shared__ int slot_s;

    const int tid = threadIdx.x, lane = tid & 63, wv = tid >> 6;
    const int l15 = lane & 15, q = lane >> 4, q8 = q << 3;

    unsigned int xcc;
    asm volatile("s_getreg_b32 %0, hwreg(HW_REG_XCC_ID)" : "=s"(xcc));
    xcc &= 7u;
    if (tid == 0) slot_s = (int)(atomicAdd(&qcnt[xcc], 1u) & 31u);
    __syncthreads();
    const int slot = slot_s;
    const int rg = ((int)xcc << 2) + (slot >> 3);
    const int hsl = slot & 7;
    const int row0 = rg << 7, hidb = hsl << 5;
    const unsigned short* pkr = pk + (size_t)xcc * PKREP;

    // stage Wih1 (mt=0) + Whh1 (mt=1) B-frags into LDS, once (plain cached)
#pragma unroll
    for (int k = 0; k < 32; ++k) {
        int sl = tid + (k << 8);
        int ln = sl & 63, kc = (sl >> 6) & 7, nf = (sl >> 9) & 7, mt = sl >> 12;
        int n = ((mt + 1) << 6) + ((nf >> 1) << 4) + (hsl << 1) + (nf & 1);
        *(short8v*)&wlds[sl << 3] =
            *(const short8v*)&pkr[((size_t)((n << 3) + kc) << 9) + (ln << 3)];
    }

    const float outb_v = outb[0];
    float wx2[2][4], bb0v[2][4], bb1v[2][4], ow2[2];
#pragma unroll
    for (int u = 0; u < 2; ++u) {
        int hid = hidb + (u << 4) + l15;
        ow2[u] = outW[hid];
#pragma unroll
        for (int g = 0; g < 4; ++g) {
            wx2[u][g]  = Wih0[(g << 8) + hid];
            bb0v[u][g] = b0[(g << 8) + hid];
            bb1v[u][g] = b1[(g << 8) + hid];
        }
    }
    float c0r[2][2][4], c1r[2][2][4];
#pragma unroll
    for (int m = 0; m < 2; ++m)
#pragma unroll
        for (int u = 0; u < 2; ++u) {
            int hid = hidb + (u << 4) + l15;
#pragma unroll
            for (int r = 0; r < 4; ++r) {
                int row = row0 + (wv << 5) + (m << 4) + (q << 2) + r;
                c0r[m][u][r] = finc0[(size_t)(row & 255) * HIDN + hid];
                c1r[m][u][r] = finc1[(size_t)(row & 255) * HIDN + hid];
            }
        }

    // af0 register-carry: preload h0(final enc) for t=0 (plain; boundary-coherent)
    short8v af0[2][8];
#pragma unroll
    for (int m = 0; m < 2; ++m) {
        int row = (row0 + (wv << 5) + (m << 4) + l15) & 255;
        const unsigned short* p = finh0 + (size_t)row * HIDN + q8;
#pragma unroll
        for (int kc = 0; kc < 8; ++kc) af0[m][kc] = *(const short8v*)&p[kc << 5];
    }

    unsigned int* fl = flags + (rg << 4);
    int dead = 0;
    __syncthreads();

    for (int t = 0; t < 64; ++t) {
        const unsigned short* h1prev = (t == 0) ? finh1 : h1d + (size_t)((t + 1) & 1) * HPD;
        unsigned short* h0w = h0d + (size_t)(t & 1) * HPD;
        unsigned short* h1w = h1d + (size_t)(t & 1) * HPD;
        const int rmask = (t == 0) ? 255 : 0x7FFFFFFF;

        // ---- phase A ----
        // pred partial loads (sc0, L2-local) or dinit
        float4v pr0 = {0,0,0,0}, pr1 = {0,0,0,0};
        if (t == 0) {
            if (tid < 128) inpl[tid] = dinit[row0 + tid];
        } else if (tid < 128) {
            const float* pb = predpart + ((size_t)((t - 1) & 1) << 15)
                            + ((size_t)(row0 + tid) << 3);
            pr0 = ld16f_sc0(pb);
            pr1 = ld16f_sc0(pb + 4);
        }

        // acc0 = h0(t-1) @ Whh0 (af0 reg-carry; B streamed from L2-hot replica)
        float4v acc0[2][8];
#pragma unroll
        for (int m = 0; m < 2; ++m)
#pragma unroll
            for (int nf = 0; nf < 8; ++nf) acc0[m][nf] = (float4v){0, 0, 0, 0};
#pragma unroll
        for (int kc = 0; kc < 8; ++kc)
#pragma unroll
            for (int nf = 0; nf < 8; ++nf) {
                int n = ((nf >> 1) << 4) + (hsl << 1) + (nf & 1);
                short8v bf = *(const short8v*)&pkr[((size_t)((n << 3) + kc) << 9) + (lane << 3)];
                acc0[0][nf] = MFMA(af0[0][kc], bf, acc0[0][nf]);
                acc0[1][nf] = MFMA(af0[1][kc], bf, acc0[1][nf]);
            }
        if (t > 0) {
            vm_drain();
            if (tid < 128) {
                float s = ((pr0[0] + pr0[1]) + (pr0[2] + pr0[3]))
                        + ((pr1[0] + pr1[1]) + (pr1[2] + pr1[3])) + outb_v;
                inpl[tid] = s;
                if (hsl == 0) {
                    int row = row0 + tid;
                    out[(size_t)(((row & 255) << 4) + (row >> 8)) * 64 + (t - 1)] = s;
                }
            }
        }
        __syncthreads();   // inpl visible

        // cell0 -> publish h0(t) (plain stores -> this XCD's L2)
#pragma unroll
        for (int m = 0; m < 2; ++m)
#pragma unroll
            for (int u = 0; u < 2; ++u) {
                int hid = hidb + (u << 4) + l15;
#pragma unroll
                for (int r = 0; r < 4; ++r) {
                    int lr = (wv << 5) + (m << 4) + (q << 2) + r;
                    int row = row0 + lr;
                    float inp = inpl[lr];
                    float gi = acc0[m][0 + u][r] + wx2[u][0] * inp + bb0v[u][0];
                    float gf = acc0[m][2 + u][r] + wx2[u][1] * inp + bb0v[u][1];
                    float gg = acc0[m][4 + u][r] + wx2[u][2] * inp + bb0v[u][2];
                    float go = acc0[m][6 + u][r] + wx2[u][3] * inp + bb0v[u][3];
                    float cn = sigf(gf) * c0r[m][u][r] + sigf(gi) * tanhf2(gg);
                    c0r[m][u][r] = cn;
                    float h0n = sigf(go) * tanhf2(cn);
                    hpair_plain(h0w, row, hid, h0n, lane);
                }
            }

        // af1 (h1(t-1)) via sc0 loads; acc1 = af1 @ Whh1 (LDS mt=1)
        short8v af1[2][8];
#pragma unroll
        for (int m = 0; m < 2; ++m) {
            int row = (row0 + (wv << 5) + (m << 4) + l15) & rmask;
            const unsigned short* p1 = h1prev + (size_t)row * HIDN + q8;
#pragma unroll
            for (int kc = 0; kc < 8; ++kc) af1[m][kc] = ld16_sc0(p1 + (kc << 5));
        }
        vm_drain();
        float4v acc1[2][8];
#pragma unroll
        for (int m = 0; m < 2; ++m)
#pragma unroll
            for (int nf = 0; nf < 8; ++nf) acc1[m][nf] = (float4v){0, 0, 0, 0};
#pragma unroll
        for (int kc = 0; kc < 8; ++kc)
#pragma unroll
            for (int nf = 0; nf < 8; ++nf) {
                short8v bf = *(const short8v*)&wlds[(size_t)(4096 + (((nf << 3) + kc) << 6) + lane) << 3];
                acc1[0][nf] = MFMA(af1[0][kc], bf, acc1[0][nf]);
                acc1[1][nf] = MFMA(af1[1][kc], bf, acc1[1][nf]);
            }
        bar_sync(fl, hsl, (unsigned int)(2 * t + 1), 8, lane, tid, dead, 1 << 16);

        // ---- phase B: af0 <- h0(t) (sc0, carried to next step); Wih1 GEMM ----
#pragma unroll
        for (int m = 0; m < 2; ++m) {
            int row = row0 + (wv << 5) + (m << 4) + l15;
            const unsigned short* p0 = h0w + (size_t)row * HIDN + q8;
#pragma unroll
            for (int kc = 0; kc < 8; ++kc) af0[m][kc] = ld16_sc0(p0 + (kc << 5));
        }
        vm_drain();
#pragma unroll
        for (int kc = 0; kc < 8; ++kc)
#pragma unroll
            for (int nf = 0; nf < 8; ++nf) {
                short8v bf = *(const short8v*)&wlds[(size_t)((((nf << 3) + kc) << 6) + lane) << 3];
                acc1[0][nf] = MFMA(af0[0][kc], bf, acc1[0][nf]);
                acc1[1][nf] = MFMA(af0[1][kc], bf, acc1[1][nf]);
            }
        // cell1 -> publish h1(t) + pred partial (plain stores)
        float pp[2][4] = {{0,0,0,0},{0,0,0,0}};
#pragma unroll
        for (int m = 0; m < 2; ++m)
#pragma unroll
            for (int u = 0; u < 2; ++u) {
                int hid = hidb + (u << 4) + l15;
#pragma unroll
                for (int r = 0; r < 4; ++r) {
                    int row = row0 + (wv << 5) + (m << 4) + (q << 2) + r;
                    float gi = acc1[m][0 + u][r] + bb1v[u][0];
                    float gf = acc1[m][2 + u][r] + bb1v[u][1];
                    float gg = acc1[m][4 + u][r] + bb1v[u][2];
                    float go = acc1[m][6 + u][r] + bb1v[u][3];
                    float cn = sigf(gf) * c1r[m][u][r] + sigf(gi) * tanhf2(gg);
                    c1r[m][u][r] = cn;
                    float h1n = sigf(go) * tanhf2(cn);
                    pp[m][r] += h1n * ow2[u];
                    hpair_plain(h1w, row, hid, h1n, lane);
                }
            }
#pragma unroll
        for (int off = 1; off < 16; off <<= 1)
#pragma unroll
            for (int m = 0; m < 2; ++m)
#pragma unroll
                for (int r = 0; r < 4; ++r) pp[m][r] += __shfl_xor(pp[m][r], off);
        if (l15 == 0) {
            float* pb = predpart + ((size_t)(t & 1) << 15);
#pragma unroll
            for (int m = 0; m < 2; ++m)
#pragma unroll
                for (int r = 0; r < 4; ++r) {
                    int row = row0 + (wv << 5) + (m << 4) + (q << 2) + r;
                    pb[((size_t)row << 3) + hsl] = pp[m][r];
                }
        }
        bar_sync(fl, hsl, (unsigned int)(2 * t + 2), 8, lane, tid, dead, 1 << 16);
    }

    // final output column t=63 (parity 1)
    if (hsl == 0 && tid < 128) {
        const float* pb = predpart + ((size_t)1 << 15) + ((size_t)(row0 + tid) << 3);
        float4v a = ld16f_sc0(pb);
        float4v b2 = ld16f_sc0(pb + 4);
        vm_drain();
        float s = ((a[0] + a[1]) + (a[2] + a[3]))
                + ((b2[0] + b2[1]) + (b2[2] + b2[3])) + outb_v;
        int row = row0 + tid;
        out[(size_t)(((row & 255) << 4) + (row >> 8)) * 64 + 63] = s;
    }
}

extern "C" void kernel_launch(void* const* d_in, const int* in_sizes, int n_in,
                              void* d_out, int out_size, void* d_ws, size_t ws_size,
                              hipStream_t stream) {
    (void)in_sizes; (void)n_in; (void)out_size; (void)ws_size;
    const float* x     = (const float*)d_in[0];
    const float* eWih0 = (const float*)d_in[1];
    const float* eWhh0 = (const float*)d_in[2];
    const float* eb0   = (const float*)d_in[3];
    const float* eWih1 = (const float*)d_in[4];
    const float* eWhh1 = (const float*)d_in[5];
    const float* eb1   = (const float*)d_in[6];
    const float* dWih0 = (const float*)d_in[7];
    const float* dWhh0 = (const float*)d_in[8];
    const float* db0   = (const float*)d_in[9];
    const float* dWih1 = (const float*)d_in[10];
    const float* dWhh1 = (const float*)d_in[11];
    const float* db1   = (const float*)d_in[12];
    const float* outW  = (const float*)d_in[13];
    const float* outb  = (const float*)d_in[14];
    const float* dinit = (const float*)d_in[15];

    char* ws = (char*)d_ws;
    unsigned short* h0e   = (unsigned short*)(ws);               // 256 KB
    unsigned short* h1e   = (unsigned short*)(ws + 262144);      // 256 KB
    unsigned short* finh0 = (unsigned short*)(ws + 524288);      // 128 KB
    unsigned short* finh1 = (unsigned short*)(ws + 655360);      // 128 KB
    float* finc0          = (float*)(ws + 786432);               // 256 KB
    float* finc1          = (float*)(ws + 1048576);              // 256 KB
    unsigned int* fle     = (unsigned int*)(ws + 1310720);       // 1 KB
    unsigned short* pk    = (unsigned short*)(ws + 1311744);     // 12 MB (8 replicas)
    unsigned int* fld     = (unsigned int*)(ws + 13894656);      // 2 KB (32 rg x 16)
    unsigned int* qcnt    = (unsigned int*)(ws + 13896704);      // 64 B (8 XCD counters)
    unsigned short* h0d   = (unsigned short*)(ws + 13896768);    // 2x2 MB
    unsigned short* h1d   = (unsigned short*)(ws + 18091072);    // 2x2 MB
    float* predpart       = (float*)(ws + 22285376);             // 256 KB [2][4096][8]

    hipMemsetAsync(fle, 0, 1024, stream);
    hipMemsetAsync(fld, 0, 2048, stream);
    hipMemsetAsync(qcnt, 0, 64, stream);

    const int dec_lds = 131072 + 512;   // weights + inpl
    hipFuncSetAttribute((const void*)dec_kernel,
                        hipFuncAttributeMaxDynamicSharedMemorySize, dec_lds);

    pack_kernel<<<384, 256, 0, stream>>>(dWhh0, dWih1, dWhh1, pk);
    enc_kernel<<<256, 256, 0, stream>>>(x, eWih0, eWhh0, eb0, eWih1, eWhh1, eb1,
                                        h0e, h1e, finh0, finh1, finc0, finc1, fle);
    dec_kernel<<<256, 256, dec_lds, stream>>>(pk, dWih0, db0, db1, outW, outb, dinit,
                                              finh0, finc0, finh1, finc1,
                                              h0d, h1d, predpart, fld, qcnt,
                                              (float*)d_out);
}